// Round 4
// baseline (113.119 us; speedup 1.0000x reference)
//
#include <hip/hip_runtime.h>
#include <hip/hip_cooperative_groups.h>

namespace cg = cooperative_groups;

// LogitDistance: out = sum_b sum_{i<j} |p[b,i]-p[b,j]| / (ntriu * B * N)
//
// Exact triangle partition at (2048-i x 128-j) granularity (unit (ih,jh)
// kept iff jh >= 16*ih; j-seg inside i-chunk -> w=0.5, above -> w=1).
// 768 blocks (3/CU, all co-resident). SINGLE cooperative dispatch:
//   partials written to distinct d_ws slots (no atomics, idempotent)
//   -> grid.sync() -> block 0 reduces 768 floats in f64, fixed order.
// No memset node, no atomic RMW tail, one graph node total.

#define NN      4096
#define THREADS 256
#define R       8      // i-values per thread (i-chunk = 2048)
#define JSEG    128    // j-values staged in LDS
#define UPB     48     // triangle units per batch row

__global__ __launch_bounds__(THREADS, 4) void pairdist_coop(
    const float* __restrict__ pred, float* __restrict__ partials,
    float* __restrict__ out, double scale, int nblocks)
{
    const int blk = blockIdx.x;
    const int b   = blk / UPB;
    const int u   = blk % UPB;

    // unit -> (ih, jh, w):  u<32: ih=0, jh=u;  u>=32: ih=1, jh=u-16
    const int   ih = (u < 32) ? 0 : 1;
    const int   jh = (u < 32) ? u : (u - 16);
    const float w  = (u >= 16 && u < 32) ? 1.0f : 0.5f;

    const float* __restrict__ row = pred + (size_t)b * NN;

    __shared__ float sj[JSEG];
    if (threadIdx.x < JSEG)
        sj[threadIdx.x] = row[jh * JSEG + threadIdx.x];

    float pi[R];
#pragma unroll
    for (int k = 0; k < R; ++k)
        pi[k] = row[ih * (THREADS * R) + k * THREADS + threadIdx.x];

    __syncthreads();

    float acc[R];
#pragma unroll
    for (int k = 0; k < R; ++k) acc[k] = 0.0f;

    // 64 VALU ops per broadcast ds_read_b128; 8 independent dep chains
#pragma unroll 4
    for (int j = 0; j < JSEG; j += 4) {
        float4 jv = *reinterpret_cast<const float4*>(&sj[j]);
#pragma unroll
        for (int k = 0; k < R; ++k) {
            acc[k] += fabsf(pi[k] - jv.x);
            acc[k] += fabsf(pi[k] - jv.y);
            acc[k] += fabsf(pi[k] - jv.z);
            acc[k] += fabsf(pi[k] - jv.w);
        }
    }

    float s = 0.0f;
#pragma unroll
    for (int k = 0; k < R; ++k) s += acc[k];

#pragma unroll
    for (int off = 32; off > 0; off >>= 1)
        s += __shfl_down(s, off, 64);

    __shared__ float sw[THREADS / 64];
    if ((threadIdx.x & 63) == 0) sw[threadIdx.x >> 6] = s;
    __syncthreads();

    if (threadIdx.x == 0) {
        float bs = (sw[0] + sw[1]) + (sw[2] + sw[3]);
        // agent-scope store: visible across non-coherent per-XCD L2s
        __hip_atomic_store(&partials[blk], bs * w, __ATOMIC_RELEASE,
                           __HIP_MEMORY_SCOPE_AGENT);
    }

    cg::this_grid().sync();

    if (blockIdx.x == 0) {
        double ds = 0.0;
        for (int i = threadIdx.x; i < nblocks; i += THREADS)
            ds += (double)__hip_atomic_load(&partials[i], __ATOMIC_RELAXED,
                                            __HIP_MEMORY_SCOPE_AGENT);
        __shared__ double sd[THREADS];
        sd[threadIdx.x] = ds;
        __syncthreads();
        for (int off = THREADS / 2; off > 0; off >>= 1) {
            if (threadIdx.x < off) sd[threadIdx.x] += sd[threadIdx.x + off];
            __syncthreads();
        }
        if (threadIdx.x == 0) out[0] = (float)(sd[0] * scale);
    }
}

extern "C" void kernel_launch(void* const* d_in, const int* in_sizes, int n_in,
                              void* d_out, int out_size, void* d_ws, size_t ws_size,
                              hipStream_t stream) {
    const float* pred = (const float*)d_in[0];
    const int total = in_sizes[0];
    const int B = total / NN;              // 16
    int nblocks = B * UPB;                 // 768 = 3 blocks/CU, co-resident

    float* partials = (float*)d_ws;
    float* outp     = (float*)d_out;

    const double ntriu = (double)NN * (double)(NN - 1) * 0.5;
    double scale = 1.0 / (ntriu * (double)B * (double)NN);

    void* args[] = { (void*)&pred, (void*)&partials, (void*)&outp,
                     (void*)&scale, (void*)&nblocks };
    hipLaunchCooperativeKernel((const void*)pairdist_coop,
                               dim3(nblocks), dim3(THREADS),
                               args, 0, stream);
}

// Round 5
// 19.460 us; speedup vs baseline: 5.8130x; 5.8130x over previous
//
#include <hip/hip_runtime.h>

// LogitDistance: out = sum_b sum_{i<j} |p[b,i]-p[b,j]| / (ntriu * B * N)
//
// Exact triangle partition at (2048-i x 128-j) granularity (unit (ih,jh)
// kept iff jh >= 16*ih; j-seg inside i-chunk -> w=0.5, above -> w=1).
// 768 equal-cost blocks (3/CU). Kernel 1 stores weighted partials to
// distinct d_ws slots (NO atomics, NO fences, NO memset). Kernel 2 is a
// single wave: 768 floats via coalesced float4 loads, f64 butterfly
// reduce in fixed order (bit-deterministic), scale, store.
//
// Cost model: R3's 768 same-address atomicAdds cost ~13us (serialized
// RMW at one line); plain stores + 1-wave finalize removes that tail.

#define NN      4096
#define THREADS 256
#define R       8      // i-values per thread (i-chunk = 2048)
#define JSEG    128    // j-values staged in LDS
#define UPB     48     // triangle units per batch row

__global__ __launch_bounds__(THREADS) void pairdist_part(
    const float* __restrict__ pred, float* __restrict__ partials)
{
    const int blk = blockIdx.x;
    const int b   = blk / UPB;
    const int u   = blk % UPB;

    // unit -> (ih, jh, w):  u<32: ih=0, jh=u;  u>=32: ih=1, jh=u-16
    const int   ih = (u < 32) ? 0 : 1;
    const int   jh = (u < 32) ? u : (u - 16);
    const float w  = (u >= 16 && u < 32) ? 1.0f : 0.5f;

    const float* __restrict__ row = pred + (size_t)b * NN;

    __shared__ float sj[JSEG];
    if (threadIdx.x < JSEG)
        sj[threadIdx.x] = row[jh * JSEG + threadIdx.x];

    float pi[R];
#pragma unroll
    for (int k = 0; k < R; ++k)
        pi[k] = row[ih * (THREADS * R) + k * THREADS + threadIdx.x];

    __syncthreads();

    float acc[R];
#pragma unroll
    for (int k = 0; k < R; ++k) acc[k] = 0.0f;

    // 64 VALU ops per broadcast ds_read_b128; 8 independent dep chains
#pragma unroll 4
    for (int j = 0; j < JSEG; j += 4) {
        float4 jv = *reinterpret_cast<const float4*>(&sj[j]);
#pragma unroll
        for (int k = 0; k < R; ++k) {
            acc[k] += fabsf(pi[k] - jv.x);
            acc[k] += fabsf(pi[k] - jv.y);
            acc[k] += fabsf(pi[k] - jv.z);
            acc[k] += fabsf(pi[k] - jv.w);
        }
    }

    float s = 0.0f;
#pragma unroll
    for (int k = 0; k < R; ++k) s += acc[k];

#pragma unroll
    for (int off = 32; off > 0; off >>= 1)
        s += __shfl_down(s, off, 64);

    __shared__ float sw[THREADS / 64];
    if ((threadIdx.x & 63) == 0) sw[threadIdx.x >> 6] = s;
    __syncthreads();

    if (threadIdx.x == 0)
        partials[blk] = ((sw[0] + sw[1]) + (sw[2] + sw[3])) * w;
}

// one wave; 768 = 3 * 64 * 4 floats, fixed-order f64 reduce
__global__ __launch_bounds__(64) void pairdist_fin(
    const float* __restrict__ partials, float* __restrict__ out, double scale)
{
    double s = 0.0;
#pragma unroll
    for (int c = 0; c < 3; ++c) {
        float4 v = *reinterpret_cast<const float4*>(
            &partials[c * 256 + threadIdx.x * 4]);
        s += ((double)v.x + (double)v.y) + ((double)v.z + (double)v.w);
    }
#pragma unroll
    for (int off = 32; off > 0; off >>= 1)
        s += __shfl_down(s, off, 64);
    if (threadIdx.x == 0) out[0] = (float)(s * scale);
}

extern "C" void kernel_launch(void* const* d_in, const int* in_sizes, int n_in,
                              void* d_out, int out_size, void* d_ws, size_t ws_size,
                              hipStream_t stream) {
    const float* pred = (const float*)d_in[0];
    const int total = in_sizes[0];
    const int B = total / NN;              // 16
    const int nblocks = B * UPB;           // 768

    float* partials = (float*)d_ws;        // 768 * 4 B, fully overwritten

    pairdist_part<<<nblocks, THREADS, 0, stream>>>(pred, partials);

    const double ntriu = (double)NN * (double)(NN - 1) * 0.5;
    const double scale = 1.0 / (ntriu * (double)B * (double)NN);
    pairdist_fin<<<1, 64, 0, stream>>>(partials, (float*)d_out, scale);
}

// Round 6
// 18.160 us; speedup vs baseline: 6.2291x; 1.0716x over previous
//
#include <hip/hip_runtime.h>

// LogitDistance: out = sum_b sum_{i<j} |p[b,i]-p[b,j]| / (ntriu * B * N)
//
// Per-WAVE triangle units of (256-i x 128-j): unit (c, jh) kept iff
// jh >= 2c.  j-seg inside i-chunk (jh in {2c,2c+1}) -> both orderings
// executed -> w=0.5; strictly above -> w=1.  Exact.
// Executed pairs/row = 272 units * 32768 = 8.91M vs true 8.39M (1.06x)
// -> 285M lane-ops total (was 403M with 2048-wide chunks).
//
// k1: 1088 blocks x 256 thr (4 waves, 1 unit each).  Each wave stages its
// private 128-float j-slice in LDS (broadcast float4 reads), R=4 i/lane,
// wave butterfly, lane0 stores weighted partial (4352 slots, no atomics,
// no fences, no end barrier).
// k2: one wave, 17 coalesced float4 loads/lane (4352 = 64*17*4), f64
// fixed-order reduce, scale, store.  Deterministic; replay-safe
// (pure overwrite semantics, no memset needed).

#define NN      4096
#define THREADS 256
#define WAVES   4
#define R       4      // i-values per lane
#define CSZ     256    // i-chunk width (64 lanes * R)
#define JSEG    128    // j-values staged per wave
#define UPR     272    // triangle units per batch row (sum_{c=0..15} 32-2c)
#define BPR     68     // blocks per row (UPR / WAVES)

__global__ __launch_bounds__(THREADS) void pairdist_part(
    const float* __restrict__ pred, float* __restrict__ partials)
{
    const int lane = threadIdx.x & 63;
    const int wid  = threadIdx.x >> 6;
    const int b    = blockIdx.x / BPR;
    int u = (blockIdx.x % BPR) * WAVES + wid;   // 0..271

    // decode u -> (c, jh, w): for c in 0..15, jh in [2c, 32), count 32-2c
    int c = 0;
    while (u >= 32 - 2 * c) { u -= 32 - 2 * c; ++c; }
    const int   jh = 2 * c + u;
    const float w  = (u < 2) ? 0.5f : 1.0f;

    const float* __restrict__ row = pred + (size_t)b * NN;

    __shared__ float sj[WAVES][JSEG];
    sj[wid][lane]      = row[jh * JSEG + lane];
    sj[wid][64 + lane] = row[jh * JSEG + 64 + lane];

    float pi[R];
#pragma unroll
    for (int k = 0; k < R; ++k)
        pi[k] = row[c * CSZ + k * 64 + lane];

    __syncthreads();   // cheap; guarantees wave's staged slice is visible

    float a0 = 0.f, a1 = 0.f, a2 = 0.f, a3 = 0.f;
#pragma unroll 8
    for (int j = 0; j < JSEG; j += 4) {
        float4 jv = *reinterpret_cast<const float4*>(&sj[wid][j]);
        a0 += fabsf(pi[0] - jv.x); a1 += fabsf(pi[1] - jv.x);
        a2 += fabsf(pi[2] - jv.x); a3 += fabsf(pi[3] - jv.x);
        a0 += fabsf(pi[0] - jv.y); a1 += fabsf(pi[1] - jv.y);
        a2 += fabsf(pi[2] - jv.y); a3 += fabsf(pi[3] - jv.y);
        a0 += fabsf(pi[0] - jv.z); a1 += fabsf(pi[1] - jv.z);
        a2 += fabsf(pi[2] - jv.z); a3 += fabsf(pi[3] - jv.z);
        a0 += fabsf(pi[0] - jv.w); a1 += fabsf(pi[1] - jv.w);
        a2 += fabsf(pi[2] - jv.w); a3 += fabsf(pi[3] - jv.w);
    }
    float s = (a0 + a1) + (a2 + a3);

#pragma unroll
    for (int off = 32; off > 0; off >>= 1)
        s += __shfl_down(s, off, 64);

    if (lane == 0)
        partials[blockIdx.x * WAVES + wid] = s * w;   // plain store
}

// one wave; 4352 = 64 lanes * 17 float4, fixed-order f64 reduce
__global__ __launch_bounds__(64) void pairdist_fin(
    const float* __restrict__ partials, float* __restrict__ out, double scale)
{
    double s = 0.0;
#pragma unroll
    for (int cc = 0; cc < 17; ++cc) {
        float4 v = *reinterpret_cast<const float4*>(
            &partials[(cc * 64 + threadIdx.x) * 4]);
        s += ((double)v.x + (double)v.y) + ((double)v.z + (double)v.w);
    }
#pragma unroll
    for (int off = 32; off > 0; off >>= 1)
        s += __shfl_down(s, off, 64);
    if (threadIdx.x == 0) out[0] = (float)(s * scale);
}

extern "C" void kernel_launch(void* const* d_in, const int* in_sizes, int n_in,
                              void* d_out, int out_size, void* d_ws, size_t ws_size,
                              hipStream_t stream) {
    const float* pred = (const float*)d_in[0];
    const int total = in_sizes[0];
    const int B = total / NN;              // 16
    const int nblocks = B * BPR;           // 1088

    float* partials = (float*)d_ws;        // 4352 * 4 B, fully overwritten

    pairdist_part<<<nblocks, THREADS, 0, stream>>>(pred, partials);

    const double ntriu = (double)NN * (double)(NN - 1) * 0.5;
    const double scale = 1.0 / (ntriu * (double)B * (double)NN);
    pairdist_fin<<<1, 64, 0, stream>>>(partials, (float*)d_out, scale);
}

// Round 7
// 18.011 us; speedup vs baseline: 6.2805x; 1.0082x over previous
//
#include <hip/hip_runtime.h>

// LogitDistance: out = sum_b sum_{i<j} |p[b,i]-p[b,j]| / (ntriu * B * N)
//
// SINGLE dispatch, fused reduce via tagged slots:
//  - compute blocks (1..1088): per-wave triangle unit (256-i x 128-j,
//    exact: jh>=2c, w=0.5 iff j-seg inside i-chunk), wave butterfly,
//    4-wave LDS combine, then ONE 8-byte relaxed agent-scope atomic store
//    of (f32 partial | MAGIC tag) to a distinct slot. No fences (tag+value
//    travel atomically together), no RMW atomics, no memset.
//  - block 0, wave 0: polls the 1088 slots (17 coalesced 8B loads/lane)
//    until all tagged, reduces in FIXED order in f64 (bit-deterministic),
//    writes d_out, clears tags for the next replay.
// Replay-safe: poisoned ws has tag 0xAAAAAAAA != MAGIC; reducer re-zeroes
// tags each call. No co-residency requirement: compute blocks never wait.

#define NN      4096
#define THREADS 256
#define WAVES   4
#define R       4      // i-values per lane
#define CSZ     256    // i-chunk width
#define JSEG    128    // j-values staged per wave
#define BPR     68     // compute blocks per batch row (272 units / 4 waves)
#define NSLOT   1088   // 16 rows * 68 blocks
#define MAGIC   0x7F3A9C51u

__global__ __launch_bounds__(THREADS) void pairdist_fused(
    const float* __restrict__ pred,
    unsigned long long* __restrict__ slots,
    float* __restrict__ out, double scale)
{
    if (blockIdx.x == 0) {
        // ---------------- reducer: one wave ----------------
        if (threadIdx.x >= 64) return;
        const int l = threadIdx.x;
        float vals[17];
        unsigned seen = 0;
        while (seen != 0x1FFFFu) {
#pragma unroll
            for (int k = 0; k < 17; ++k) {
                if (!(seen & (1u << k))) {
                    unsigned long long p = __hip_atomic_load(
                        &slots[l + 64 * k], __ATOMIC_RELAXED,
                        __HIP_MEMORY_SCOPE_AGENT);
                    if ((unsigned)(p >> 32) == MAGIC) {
                        vals[k] = __uint_as_float((unsigned)p);
                        seen |= 1u << k;
                    }
                }
            }
            __builtin_amdgcn_s_sleep(2);
        }
        double s = 0.0;
#pragma unroll
        for (int k = 0; k < 17; ++k) s += (double)vals[k];   // fixed order
#pragma unroll
        for (int off = 32; off > 0; off >>= 1)
            s += __shfl_down(s, off, 64);                    // fixed order
        if (l == 0) out[0] = (float)(s * scale);
        // clear tags so the next replay starts untagged
#pragma unroll
        for (int k = 0; k < 17; ++k) {
            unsigned* tag = ((unsigned*)&slots[l + 64 * k]) + 1;
            __hip_atomic_store(tag, 0u, __ATOMIC_RELAXED,
                               __HIP_MEMORY_SCOPE_AGENT);
        }
        return;
    }

    // ---------------- compute blocks ----------------
    const int cb   = blockIdx.x - 1;            // 0..1087
    const int lane = threadIdx.x & 63;
    const int wid  = threadIdx.x >> 6;
    const int b    = cb / BPR;
    int u = (cb % BPR) * WAVES + wid;           // 0..271

    // decode u -> (c, jh, w): for c in 0..15, jh in [2c, 32)
    int c = 0;
    while (u >= 32 - 2 * c) { u -= 32 - 2 * c; ++c; }
    const int   jh = 2 * c + u;
    const float w  = (u < 2) ? 0.5f : 1.0f;

    const float* __restrict__ row = pred + (size_t)b * NN;

    __shared__ float sj[WAVES][JSEG];   // wave-private slices: no barrier
    __shared__ float sw[WAVES];
    sj[wid][lane]      = row[jh * JSEG + lane];
    sj[wid][64 + lane] = row[jh * JSEG + 64 + lane];

    float pi[R];
#pragma unroll
    for (int k = 0; k < R; ++k)
        pi[k] = row[c * CSZ + k * 64 + lane];

    float a0 = 0.f, a1 = 0.f, a2 = 0.f, a3 = 0.f;
#pragma unroll 8
    for (int j = 0; j < JSEG; j += 4) {
        float4 jv = *reinterpret_cast<const float4*>(&sj[wid][j]);
        a0 += fabsf(pi[0] - jv.x); a1 += fabsf(pi[1] - jv.x);
        a2 += fabsf(pi[2] - jv.x); a3 += fabsf(pi[3] - jv.x);
        a0 += fabsf(pi[0] - jv.y); a1 += fabsf(pi[1] - jv.y);
        a2 += fabsf(pi[2] - jv.y); a3 += fabsf(pi[3] - jv.y);
        a0 += fabsf(pi[0] - jv.z); a1 += fabsf(pi[1] - jv.z);
        a2 += fabsf(pi[2] - jv.z); a3 += fabsf(pi[3] - jv.z);
        a0 += fabsf(pi[0] - jv.w); a1 += fabsf(pi[1] - jv.w);
        a2 += fabsf(pi[2] - jv.w); a3 += fabsf(pi[3] - jv.w);
    }
    float s = (a0 + a1) + (a2 + a3);

#pragma unroll
    for (int off = 32; off > 0; off >>= 1)
        s += __shfl_down(s, off, 64);

    if (lane == 0) sw[wid] = s * w;
    __syncthreads();

    if (threadIdx.x == 0) {
        float bs = (sw[0] + sw[1]) + (sw[2] + sw[3]);   // fixed order
        unsigned long long p = ((unsigned long long)MAGIC << 32) |
                               (unsigned long long)__float_as_uint(bs);
        __hip_atomic_store(&slots[cb], p, __ATOMIC_RELAXED,
                           __HIP_MEMORY_SCOPE_AGENT);
    }
}

extern "C" void kernel_launch(void* const* d_in, const int* in_sizes, int n_in,
                              void* d_out, int out_size, void* d_ws, size_t ws_size,
                              hipStream_t stream) {
    const float* pred = (const float*)d_in[0];
    const int total = in_sizes[0];
    const int B = total / NN;                    // 16
    const int nblocks = 1 + B * BPR;             // 1089 (block 0 = reducer)

    unsigned long long* slots = (unsigned long long*)d_ws;  // 1088 * 8 B

    const double ntriu = (double)NN * (double)(NN - 1) * 0.5;
    const double scale = 1.0 / (ntriu * (double)B * (double)NN);

    pairdist_fused<<<nblocks, THREADS, 0, stream>>>(
        pred, slots, (float*)d_out, scale);
}